// Round 3
// baseline (72.542 us; speedup 1.0000x reference)
//
#include <hip/hip_runtime.h>

#define C_IN  32
#define C_OUT 64
#define HH    64
#define WW    64
#define IC_PB 8          // ic per block (quarter)
#define ICS   190        // LDS dwords per ic slice: 10 rows * 19
#define ROWS  19         // row stride: two 9-wide parity halves + 1 pad (odd)

// ---------------------------------------------------------------------------
// Weight-product precompute, k-major: Wt[((p*32+ic)*9+k)*64 + oc]
// W~_k = Ew(k) * (w_k if (p+k) odd), Ew(k) = prod_{j>=k, (p+j) even} w_j
// ---------------------------------------------------------------------------
__global__ void wprod_kernel(const float* __restrict__ w, float* __restrict__ Wt) {
    int t = blockIdx.x * 256 + threadIdx.x;
    if (t >= 2 * C_IN * C_OUT) return;
    int oc = t & 63;
    int ic = (t >> 6) & 31;
    int p  = t >> 11;
    const float* wp = w + (oc * C_IN + ic) * 9;
    float W[9];
    float Ew = 1.f;
    #pragma unroll
    for (int k = 8; k >= 0; --k) {
        float wk = wp[k];
        if (((p + k) & 1) == 0) { Ew *= wk; W[k] = Ew; }
        else                    { W[k] = wk * Ew; }
    }
    #pragma unroll
    for (int k = 0; k < 9; ++k)
        Wt[((p * C_IN + ic) * 9 + k) * C_OUT + oc] = W[k];
}

#if defined(__has_builtin) && __has_builtin(__builtin_amdgcn_global_atomic_fadd_f32)
#define ATOMIC_FADD(p, v) unsafeAtomicAdd((p), (v))
#else
#define ATOMIC_FADD(p, v) atomicAdd((p), (v))
#endif

// ---------------------------------------------------------------------------
// Main kernel. Block = 8x16 spatial tile (one n) x 32 oc x 8 ic (quarter).
// 256 threads = 4 waves; wave w: parity p = w&1, oc group og = w>>1.
// Lane = one checkerboard position of that parity -> W~ address wave-uniform
// (scalar s_loads). LDS x-tile is parity-split: xs[ic][row][q][h], q = col&1,
// h = col>>1, row stride 19 (odd) -> taps spread across banks.
// ---------------------------------------------------------------------------
template<int P>
__device__ __forceinline__ void aeg_body(
    const float* __restrict__ Wt, const float* __restrict__ xs,
    int oc0, int icg0, int r, int cj, int n, int gi, int gj,
    float* __restrict__ out)
{
    float acc[16];
    #pragma unroll
    for (int o = 0; o < 16; ++o) acc[o] = 0.f;

    const int w0 = (P + r) & 1;
    // side taps (staged cols s = c, c+2 -> half q=w0, h=cj, cj+1)
    const float* ps = xs + (r * ROWS + w0 * 9 + cj);
    // center tap (staged col s = c+1 -> half q=1-w0, h=cj+w0)
    const float* pc = xs + (r * ROWS + (1 - w0) * 9 + cj + w0);

    const float* wr = Wt + (size_t)((P * C_IN + icg0) * 9) * C_OUT + oc0;

    for (int ic = 0; ic < IC_PB; ++ic) {
        float xv[9];
        #pragma unroll
        for (int dh = 0; dh < 3; ++dh) {
            xv[dh * 3 + 0] = ps[dh * ROWS + 0];
            xv[dh * 3 + 2] = ps[dh * ROWS + 1];
            xv[dh * 3 + 1] = pc[dh * ROWS];
        }
        ps += ICS; pc += ICS;

        // X~_k: suffix products of odd-step x's; even steps multiply own x.
        float Xt[9];
        float Ox = 1.f;
        #pragma unroll
        for (int k = 8; k >= 0; --k) {
            if (((P + k) & 1) == 1) { Ox *= xv[k]; Xt[k] = Ox; }
            else                    { Xt[k] = xv[k] * Ox; }
        }

        #pragma unroll
        for (int k = 0; k < 9; ++k) {
            const float* wk = wr + k * C_OUT;
            #pragma unroll
            for (int o = 0; o < 16; ++o)
                acc[o] = fmaf(Xt[k], wk[o], acc[o]);
        }
        wr += 9 * C_OUT;
    }

    float* op = out + ((n * C_OUT + oc0) * HH + gi) * WW + gj;
    #pragma unroll
    for (int o = 0; o < 16; ++o)
        ATOMIC_FADD(op + o * (HH * WW), acc[o]);
}

__global__ __launch_bounds__(256, 8) void aeg_main(
    const float* __restrict__ x, const float* __restrict__ Wt,
    float* __restrict__ out)
{
    __shared__ float xs[IC_PB * ICS];

    int bid = blockIdx.x;
    int oh = bid & 1;          // oc half (0..1)
    int tc = (bid >> 1) & 3;   // col tile (0..3), 16 cols each
    int tr = (bid >> 3) & 7;   // row tile (0..7), 8 rows each
    int iq = (bid >> 6) & 3;   // ic quarter (0..3)
    int n  = bid >> 8;         // batch (0..7)
    int tid = threadIdx.x;

    // Stage padded x tile (rows tr*8-1..+8, cols tc*16-1..+16), parity-split.
    for (int ll = tid; ll < IC_PB * 10 * 18; ll += 256) {
        int ic  = ll / 180;
        int rem = ll - ic * 180;
        int rr  = rem / 18;
        int s   = rem - rr * 18;          // staged col 0..17 (= local col + 1)
        int gi  = tr * 8 + rr - 1;
        int gj  = tc * 16 + s - 1;
        float v = 0.f;
        if ((unsigned)gi < 64u && (unsigned)gj < 64u)
            v = x[((n * C_IN + iq * IC_PB + ic) * HH + gi) * WW + gj];
        xs[ic * ICS + rr * ROWS + (s & 1) * 9 + (s >> 1)] = v;
    }
    __syncthreads();

    int wv = __builtin_amdgcn_readfirstlane(tid >> 6); // wave id 0..3
    int p  = wv & 1;
    int og = wv >> 1;                                  // 0..1
    int oc0 = oh * 32 + og * 16;
    int icg0 = iq * IC_PB;

    int l = tid & 63;
    int r = l >> 3;                                    // 0..7
    int cj = l & 7;                                    // col pair index
    int c  = (cj << 1) + ((p + r) & 1);                // checkerboard col
    int gi = tr * 8 + r, gj = tc * 16 + c;

    if (p == 0) aeg_body<0>(Wt, xs, oc0, icg0, r, cj, n, gi, gj, out);
    else        aeg_body<1>(Wt, xs, oc0, icg0, r, cj, n, gi, gj, out);
}

extern "C" void kernel_launch(void* const* d_in, const int* in_sizes, int n_in,
                              void* d_out, int out_size, void* d_ws, size_t ws_size,
                              hipStream_t stream) {
    const float* x = (const float*)d_in[0];
    const float* w = (const float*)d_in[1];
    float* out = (float*)d_out;
    float* Wt  = (float*)d_ws;   // needs 2*32*9*64*4 = 147,456 bytes

    hipMemsetAsync(out, 0, (size_t)out_size * sizeof(float), stream);
    wprod_kernel<<<16, 256, 0, stream>>>(w, Wt);
    aeg_main<<<2048, 256, 0, stream>>>(x, Wt, out);
}

// Round 4
// 26.882 us; speedup vs baseline: 2.6985x; 2.6985x over previous
//
#include <hip/hip_runtime.h>

#define C_IN  32
#define C_OUT 64
#define HH    64
#define WW    64

typedef __attribute__((ext_vector_type(8))) short short8v;
typedef __attribute__((ext_vector_type(4))) float f32x4;

static __device__ __forceinline__ unsigned short f2bf(float f) {
    unsigned u = __builtin_bit_cast(unsigned, f);
    unsigned r = (u + 0x7FFFu + ((u >> 16) & 1u)) >> 16;   // RNE
    return (unsigned short)r;
}
static __device__ __forceinline__ float bf2f(unsigned short b) {
    unsigned u = ((unsigned)b) << 16;
    return __builtin_bit_cast(float, u);
}

// ---------------------------------------------------------------------------
// Weight-product + B-fragment pack.
// W~_k = Ew(k) * (w_k if (p+k) odd), Ew(k) = prod_{j>=k, (p+j) even} w_j
// Packed per-lane-contiguous for mfma_f32_16x16x32_bf16 B-frags:
//   Bpk[p][part(h=0,l=1)][k(9)][octile(4)][lane(64)][j(8)]  (bf16)
//   lane = (ic>>3)*16 + (oc&15), j = ic&7, octile = oc>>4
// Total 2*2*9*4*64*8*2B = 147,456 bytes in d_ws.
// ---------------------------------------------------------------------------
__global__ void wprod_pack(const float* __restrict__ w, unsigned short* __restrict__ Bpk) {
    int t = blockIdx.x * 256 + threadIdx.x;
    if (t >= 2 * C_IN * C_OUT) return;
    int oc = t & 63;
    int ic = (t >> 6) & 31;
    int p  = t >> 11;
    const float* wp = w + (oc * C_IN + ic) * 9;
    float W[9];
    float Ew = 1.f;
    #pragma unroll
    for (int k = 8; k >= 0; --k) {
        float wk = wp[k];
        if (((p + k) & 1) == 0) { Ew *= wk; W[k] = Ew; }
        else                    { W[k] = wk * Ew; }
    }
    int lane = ((ic >> 3) << 4) + (oc & 15);
    int j    = ic & 7;
    int oct  = oc >> 4;
    #pragma unroll
    for (int k = 0; k < 9; ++k) {
        unsigned short hi = f2bf(W[k]);
        unsigned short lo = f2bf(W[k] - bf2f(hi));
        size_t ih = ((((size_t)(p * 2 + 0) * 9 + k) * 4 + oct) * 64 + lane) * 8 + j;
        size_t il = ((((size_t)(p * 2 + 1) * 9 + k) * 4 + oct) * 64 + lane) * 8 + j;
        Bpk[ih] = hi;
        Bpk[il] = lo;
    }
}

// ---------------------------------------------------------------------------
// GEMM body (parity compile-time). xt[a][k] holds this lane's taps for
// ic = icb+a; transformed in place to X~. 3-term split GEMM:
// C = Xh*Wh + Xl*Wh + Xh*Wl  (Xl*Wl ~ 2^-18, dropped).
// ---------------------------------------------------------------------------
template<int P>
__device__ __forceinline__ void aeg_gemm(
    float (&xt)[8][9], const short8v* __restrict__ Bq,
    float* __restrict__ out, int n, int i0, int grp, int l)
{
    // X~: suffix products of odd-step x's; even steps multiply own x.
    #pragma unroll
    for (int a = 0; a < 8; ++a) {
        float Ox = 1.f;
        #pragma unroll
        for (int k = 8; k >= 0; --k) {
            if (((P + k) & 1) == 1) { Ox *= xt[a][k]; xt[a][k] = Ox; }
            else                    { xt[a][k] = xt[a][k] * Ox; }
        }
    }

    f32x4 acc[4];
    #pragma unroll
    for (int t = 0; t < 4; ++t) acc[t] = (f32x4){0.f, 0.f, 0.f, 0.f};

    const int base_h = (P * 2 + 0) * 9;
    const int base_l = (P * 2 + 1) * 9;

    #pragma unroll
    for (int k = 0; k < 9; ++k) {
        short8v ah, al;
        #pragma unroll
        for (int a = 0; a < 8; ++a) {
            float v = xt[a][k];
            unsigned short h = f2bf(v);
            ah[a] = (short)h;
            al[a] = (short)f2bf(v - bf2f(h));
        }
        #pragma unroll
        for (int t = 0; t < 4; ++t) {
            short8v bh = Bq[((base_h + k) * 4 + t) * 64 + l];
            short8v bl = Bq[((base_l + k) * 4 + t) * 64 + l];
            acc[t] = __builtin_amdgcn_mfma_f32_16x16x32_bf16(ah, bh, acc[t], 0, 0, 0);
            acc[t] = __builtin_amdgcn_mfma_f32_16x16x32_bf16(al, bh, acc[t], 0, 0, 0);
            acc[t] = __builtin_amdgcn_mfma_f32_16x16x32_bf16(ah, bl, acc[t], 0, 0, 0);
        }
    }

    // Scatter C: row = (l>>4)*4 + r (position), col = l&15 (oc low).
    int colc = l & 15;
    int rgrp = l >> 4;
    #pragma unroll
    for (int t = 0; t < 4; ++t) {
        int oc = t * 16 + colc;
        #pragma unroll
        for (int r = 0; r < 4; ++r) {
            int q = grp * 16 + rgrp * 4 + r;
            int i = i0 + (q >> 5);
            int j = 2 * (q & 31) + ((i + P) & 1);
            out[(((size_t)n * C_OUT + oc) * HH + i) * WW + j] = acc[t][r];
        }
    }
}

// ---------------------------------------------------------------------------
// Main kernel: block = 1 n x 2 rows x 64 cols, 512 threads = 8 waves.
// Wave w: parity p = w&1, M-group grp = w>>1 (16 positions of that parity).
// Lane l: A-row = grp*16 + (l&15) -> (i,j); K-elems = ic (l>>4)*8 + j.
// A-frags built in registers from 72 global taps (no LDS at all).
// ---------------------------------------------------------------------------
__global__ __launch_bounds__(512) void aeg_mfma(
    const float* __restrict__ x, const unsigned short* __restrict__ Bpk,
    float* __restrict__ out)
{
    int bid = blockIdx.x;
    int br  = bid & 31;        // row-block (0..31), 2 rows each
    int n   = bid >> 5;        // batch (0..7)
    int i0  = br * 2;
    int tid = threadIdx.x;
    int w   = __builtin_amdgcn_readfirstlane(tid >> 6);  // wave 0..7
    int p   = w & 1;
    int grp = w >> 1;          // 0..3
    int l   = tid & 63;

    int qA = grp * 16 + (l & 15);
    int iA = i0 + (qA >> 5);
    int jA = 2 * (qA & 31) + ((iA + p) & 1);
    int icb = (l >> 4) * 8;

    float xt[8][9];
    #pragma unroll
    for (int a = 0; a < 8; ++a) {
        const float* xb = x + ((size_t)n * C_IN + icb + a) * (HH * WW);
        #pragma unroll
        for (int di = 0; di < 3; ++di) {
            int ii = iA + di - 1;
            #pragma unroll
            for (int dj = 0; dj < 3; ++dj) {
                int jj = jA + dj - 1;
                bool ok = ((unsigned)ii < 64u) && ((unsigned)jj < 64u);
                xt[a][di * 3 + dj] = ok ? xb[ii * WW + jj] : 0.f;
            }
        }
    }

    const short8v* Bq = (const short8v*)Bpk;
    if (p == 0) aeg_gemm<0>(xt, Bq, out, n, i0, grp, l);
    else        aeg_gemm<1>(xt, Bq, out, n, i0, grp, l);
}

extern "C" void kernel_launch(void* const* d_in, const int* in_sizes, int n_in,
                              void* d_out, int out_size, void* d_ws, size_t ws_size,
                              hipStream_t stream) {
    const float* x = (const float*)d_in[0];
    const float* w = (const float*)d_in[1];
    float* out = (float*)d_out;
    unsigned short* Bpk = (unsigned short*)d_ws;   // 147,456 bytes

    wprod_pack<<<16, 256, 0, stream>>>(w, Bpk);
    aeg_mfma<<<256, 512, 0, stream>>>(x, Bpk, out);
}